// Round 4
// baseline (582.397 us; speedup 1.0000x reference)
//
#include <hip/hip_runtime.h>
#include <stdint.h>

typedef _Float16 half_t;
typedef __attribute__((ext_vector_type(8))) _Float16 f16x8;
typedef __attribute__((ext_vector_type(4))) _Float16 f16x4;
typedef __attribute__((ext_vector_type(4))) float f32x4;

#define DEVI __device__ __forceinline__

static constexpr int Bn = 4, Cc = 256, Nn = 4096, PD = 32;
static constexpr float L2E = 1.44269504089f;

// persistent f16 intermediates (module-scope device memory; fully rewritten every call)
__device__ half_t g_Q[(size_t)Bn * Nn * PD];   // [b][n][d]
__device__ half_t g_K[(size_t)Bn * Nn * PD];   // [b][n][d]  (= k^T)
__device__ half_t g_V[(size_t)Bn * Cc * Nn];   // [b][e][n]

DEVI f16x8 cvt8(float4 a, float4 b) {
    f16x8 r;
    r[0] = (_Float16)a.x; r[1] = (_Float16)a.y; r[2] = (_Float16)a.z; r[3] = (_Float16)a.w;
    r[4] = (_Float16)b.x; r[5] = (_Float16)b.y; r[6] = (_Float16)b.z; r[7] = (_Float16)b.w;
    return r;
}

// async global->LDS, 16B per lane; LDS dest is wave-uniform base + lane*16
DEVI void gll16(const void* g, void* l) {
    auto gp = (const __attribute__((address_space(1))) uint32_t*)(uintptr_t)g;
    auto lp = (__attribute__((address_space(3))) uint32_t*)(uintptr_t)l;
    __builtin_amdgcn_global_load_lds(gp, lp, 16, 0, 0);
}

// ---------------- projection: Q,K,V = W @ x (+bias), f16 outputs ----------------
__global__ __launch_bounds__(256, 1) void proj_kernel(
    const float* __restrict__ x,
    const float* __restrict__ Wq, const float* __restrict__ bq,
    const float* __restrict__ Wk, const float* __restrict__ bk,
    const float* __restrict__ Wv, const float* __restrict__ bv)
{
    __shared__ __align__(16) half_t xt[64 * 40];   // [n][c] tile, pad 32->40

    const int b    = blockIdx.x >> 6;
    const int n0   = (blockIdx.x & 63) * 64;
    const int t    = threadIdx.x;
    const int w    = t >> 6;
    const int lane = t & 63;
    const int l15  = lane & 15, g = lane >> 4;

    f32x4 qk_acc[4] = {};
    f32x4 v_acc[4][4] = {};

    const float* wrow_qk = (w < 2) ? (Wq + (size_t)(16 * w + l15) * Cc)
                                   : (Wk + (size_t)(16 * (w - 2) + l15) * Cc);

    for (int cs = 0; cs < 8; ++cs) {
        const int c0 = cs * 32;
        {
            const int nl = t & 63;
            const int cg = t >> 6;
            const float* xp = x + ((size_t)(b * Cc + c0 + cg * 8)) * Nn + n0 + nl;
            float f[8];
#pragma unroll
            for (int q = 0; q < 8; ++q) f[q] = xp[(size_t)q * Nn];
            f16x4 h0, h1;
#pragma unroll
            for (int q = 0; q < 4; ++q) { h0[q] = (_Float16)f[q]; h1[q] = (_Float16)f[q + 4]; }
            *(f16x4*)&xt[nl * 40 + cg * 8]     = h0;
            *(f16x4*)&xt[nl * 40 + cg * 8 + 4] = h1;
        }
        __syncthreads();

        f16x8 xf[4];
#pragma unroll
        for (int nf = 0; nf < 4; ++nf)
            xf[nf] = *(const f16x8*)&xt[(nf * 16 + l15) * 40 + g * 8];

        {
            const float* wp = wrow_qk + c0 + g * 8;
            const f16x8 af = cvt8(*(const float4*)wp, *(const float4*)(wp + 4));
#pragma unroll
            for (int nt = 0; nt < 4; ++nt)
                qk_acc[nt] = __builtin_amdgcn_mfma_f32_16x16x32_f16(af, xf[nt], qk_acc[nt], 0, 0, 0);
        }
#pragma unroll
        for (int et = 0; et < 4; ++et) {
            const int e = (w * 4 + et) * 16 + l15;
            const float* wp = Wv + (size_t)e * Cc + c0 + g * 8;
            const f16x8 wf = cvt8(*(const float4*)wp, *(const float4*)(wp + 4));
#pragma unroll
            for (int nf = 0; nf < 4; ++nf)
                v_acc[et][nf] = __builtin_amdgcn_mfma_f32_16x16x32_f16(xf[nf], wf, v_acc[et][nf], 0, 0, 0);
        }
        __syncthreads();
    }

    {
        const float* bias = (w < 2) ? bq : bk;
        const int dbase = 16 * (w & 1) + 4 * g;
        float bb[4];
#pragma unroll
        for (int r = 0; r < 4; ++r) bb[r] = bias[dbase + r];
        half_t* dst = (w < 2) ? g_Q : g_K;
#pragma unroll
        for (int nt = 0; nt < 4; ++nt) {
            const int n = n0 + nt * 16 + l15;
            f16x4 h;
#pragma unroll
            for (int r = 0; r < 4; ++r) h[r] = (_Float16)(qk_acc[nt][r] + bb[r]);
            *(f16x4*)&dst[((size_t)b * Nn + n) * PD + dbase] = h;
        }
    }
#pragma unroll
    for (int et = 0; et < 4; ++et) {
        const int e = (w * 4 + et) * 16 + l15;
        const float bve = bv[e];
#pragma unroll
        for (int nf = 0; nf < 4; ++nf) {
            const int n = n0 + nf * 16 + 4 * g;
            f16x4 h;
#pragma unroll
            for (int r = 0; r < 4; ++r) h[r] = (_Float16)(v_acc[et][nf][r] + bve);
            *(f16x4*)&g_V[((size_t)b * Cc + e) * Nn + n] = h;
        }
    }
}

// ---------------- fused flash attention + residual (v4: kk-split, R=2) ----------
// Block = 64m x 128e, 4 waves: wave (mh=w>>1, kk=w&1) handles 32m x 128e over its
// 32n half of each 64n tile.  Softmax split over n: per-iter cross-wave row-max
// exchange via LDS (folded into the ONE barrier); l and acc partials merged once
// at the end (alphas bit-identical across the kk-pair by construction).
// V staged by global_load_lds with pre-swizzled SOURCE addrs (linear LDS dest).
// Grid 512 = [mt:64]x[b:4 x eh:2 as XCD group]: bid = mt*8 + grp so all 64
// blocks of one (b,eh) share one XCD's L2 (V-slice 1MB + K 256KB < 4MB).
__global__ __launch_bounds__(256, 2) void attn_kernel(
    const float* __restrict__ x, const float* __restrict__ gamma_p, float* __restrict__ out)
{
    __shared__ __align__(16) half_t V_lds[2][128 * 64];   // linear [e][n], 32KB
    __shared__ __align__(16) half_t P_lds[4][32 * 40];    // per-wave [m][n], padded
    __shared__ float hmx[2][2][32];                       // [kk][mh][m-local]
    __shared__ float lx[2][2][32];

    const int blk = blockIdx.x;
    const int grp = blk & 7;
    const int mt  = blk >> 3;
    const int b   = grp >> 1;
    const int eh  = grp & 1;
    const int e0  = eh * 128;

    const int t    = threadIdx.x;
    const int w    = t >> 6;
    const int lane = t & 63;
    const int l15  = lane & 15, g = lane >> 4;
    const int mh   = w >> 1, kk = w & 1;
    const int mrow0 = mt * 64 + mh * 32;

    const half_t* Kb  = g_K + (size_t)b * Nn * PD;
    const half_t* Vbg = g_V + (size_t)b * Cc * Nn;

    f16x8 qf[2];
#pragma unroll
    for (int m2 = 0; m2 < 2; ++m2)
        qf[m2] = *(const f16x8*)&g_Q[((size_t)b * Nn + mrow0 + m2 * 16 + l15) * PD + g * 8];

    // K pointers: wave's 32n window
    const half_t* kptr[2];
#pragma unroll
    for (int tt = 0; tt < 2; ++tt)
        kptr[tt] = Kb + (size_t)(kk * 32 + tt * 16 + l15) * PD + g * 8;

    // V gll pointers: lane covers (row = lane>>3, 16B chunk lane&7), source col
    // pre-swizzled so linear LDS == swizzled layout
    const int vrow = lane >> 3;
    const int vcol = (((lane & 7) ^ vrow) * 8);
    const half_t* vptr[4];
#pragma unroll
    for (int ch = 0; ch < 4; ++ch)
        vptr[ch] = Vbg + (size_t)(e0 + w * 32 + ch * 8 + vrow) * Nn + vcol;

    f32x4 acc[2][8] = {};                     // [m2][et]; rows m=4g+r, col e=et*16+l15
    float run_m[2] = {-1e30f, -1e30f};
    float run_l[2] = {0.f, 0.f};
    f16x8 kf[2], kfn[2];

    const int xorv = (kk * 32 + 8 * g) ^ ((l15 & 7) * 8);   // V read col offset

    // prologue: V tile 0 -> buf0, K tile 0 -> regs
#pragma unroll
    for (int ch = 0; ch < 4; ++ch)
        gll16(vptr[ch], &V_lds[0][(w * 32 + ch * 8) * 64]);
#pragma unroll
    for (int tt = 0; tt < 2; ++tt)
        kf[tt] = *(const f16x8*)kptr[tt];

    for (int i = 0; i < Nn / 64; ++i) {
        const int buf = i & 1;
        const bool more = (i < Nn / 64 - 1);

        // 1. QK^T (swapped): s[m2][tt] -> S[n = kk*32+tt*16+4g+r][m = mrow0+m2*16+l15]
        f32x4 s[2][2];
        const f32x4 zero = {0.f, 0.f, 0.f, 0.f};
#pragma unroll
        for (int m2 = 0; m2 < 2; ++m2)
#pragma unroll
            for (int tt = 0; tt < 2; ++tt)
                s[m2][tt] = __builtin_amdgcn_mfma_f32_16x16x32_f16(kf[tt], qf[m2], zero, 0, 0, 0);

        // 2. wave-local row max (8 vals, tree) + publish
        float hm[2];
#pragma unroll
        for (int m2 = 0; m2 < 2; ++m2) {
            float a0 = fmaxf(s[m2][0][0], s[m2][0][1]), a1 = fmaxf(s[m2][0][2], s[m2][0][3]);
            float a2 = fmaxf(s[m2][1][0], s[m2][1][1]), a3 = fmaxf(s[m2][1][2], s[m2][1][3]);
            float v = fmaxf(fmaxf(a0, a1), fmaxf(a2, a3));
            v = fmaxf(v, __shfl_xor(v, 16));
            v = fmaxf(v, __shfl_xor(v, 32));
            hm[m2] = v;
        }
        if (lane < 32) hmx[kk][mh][lane] = (lane < 16) ? hm[0] : hm[1];

        // 3. the ONE barrier (also drains prev gll + guards V buf reuse)
        __syncthreads();

        // 4. issue next tile (V via gll into other buf; K into regs)
        if (more) {
#pragma unroll
            for (int ch = 0; ch < 4; ++ch) {
                vptr[ch] += 64;
                gll16(vptr[ch], &V_lds[buf ^ 1][(w * 32 + ch * 8) * 64]);
            }
#pragma unroll
            for (int tt = 0; tt < 2; ++tt) {
                kptr[tt] += 64 * PD;
                kfn[tt] = *(const f16x8*)kptr[tt];
            }
        }

        // 5. combined max, defer-max, exp, l-update, P write
        float tm[2];
#pragma unroll
        for (int m2 = 0; m2 < 2; ++m2)
            tm[m2] = fmaxf(hm[m2], hmx[kk ^ 1][mh][m2 * 16 + l15]);

        const bool upd = (tm[0] > run_m[0] + 8.f) || (tm[1] > run_m[1] + 8.f);
        float alpha[2] = {1.f, 1.f};
        if (__any(upd)) {
#pragma unroll
            for (int m2 = 0; m2 < 2; ++m2) {
                const float nm = fmaxf(run_m[m2], tm[m2]);
                alpha[m2] = __builtin_amdgcn_exp2f((run_m[m2] - nm) * L2E);
                run_m[m2] = nm;
            }
            float a4[2][4];
#pragma unroll
            for (int m2 = 0; m2 < 2; ++m2)
#pragma unroll
                for (int r = 0; r < 4; ++r) a4[m2][r] = __shfl(alpha[m2], 4 * g + r);
#pragma unroll
            for (int m2 = 0; m2 < 2; ++m2)
#pragma unroll
                for (int et = 0; et < 8; ++et)
#pragma unroll
                    for (int r = 0; r < 4; ++r) acc[m2][et][r] *= a4[m2][r];
        }

#pragma unroll
        for (int m2 = 0; m2 < 2; ++m2) {
            const float nms = run_m[m2] * L2E;
            float pv[2][4];
#pragma unroll
            for (int tt = 0; tt < 2; ++tt) {
                f16x4 h;
#pragma unroll
                for (int r = 0; r < 4; ++r) {
                    pv[tt][r] = __builtin_amdgcn_exp2f(s[m2][tt][r] * L2E - nms);
                    h[r] = (_Float16)pv[tt][r];
                }
                *(f16x4*)&P_lds[w][(m2 * 16 + l15) * 40 + tt * 16 + 4 * g] = h;
            }
            float rs = ((pv[0][0] + pv[0][1]) + (pv[0][2] + pv[0][3]))
                     + ((pv[1][0] + pv[1][1]) + (pv[1][2] + pv[1][3]));
            rs += __shfl_xor(rs, 16);
            rs += __shfl_xor(rs, 32);
            run_l[m2] = run_l[m2] * alpha[m2] + rs;
        }

        // 6. PV over wave's 32n half: A = P (padded), B = V (swizzled read)
        f16x8 pf[2];
#pragma unroll
        for (int m2 = 0; m2 < 2; ++m2)
            pf[m2] = *(const f16x8*)&P_lds[w][(m2 * 16 + l15) * 40 + g * 8];

        __builtin_amdgcn_s_setprio(1);
#pragma unroll
        for (int et = 0; et < 8; ++et) {
            const int el = et * 16 + l15;
            const f16x8 vf = *(const f16x8*)&V_lds[buf][el * 64 + xorv];
            acc[0][et] = __builtin_amdgcn_mfma_f32_16x16x32_f16(pf[0], vf, acc[0][et], 0, 0, 0);
            acc[1][et] = __builtin_amdgcn_mfma_f32_16x16x32_f16(pf[1], vf, acc[1][et], 0, 0, 0);
        }
        __builtin_amdgcn_s_setprio(0);

        kf[0] = kfn[0];
        kf[1] = kfn[1];
    }

    // ---- epilogue: merge kk-pair partials, normalize, gamma, residual ----
    if (lane < 32) lx[kk][mh][lane] = (lane < 16) ? run_l[0] : run_l[1];
    __syncthreads();

    float linv[2][4];
#pragma unroll
    for (int m2 = 0; m2 < 2; ++m2) {
        const float lt  = run_l[m2] + lx[kk ^ 1][mh][m2 * 16 + l15];
        const float inv = 1.0f / lt;
#pragma unroll
        for (int r = 0; r < 4; ++r) linv[m2][r] = __shfl(inv, 4 * g + r);
    }

    const float gm = gamma_p[0];
    float* mrg = (float*)&V_lds[0][0];            // reuse V LDS (need 18KB < 32KB)
#pragma unroll 1
    for (int h = 0; h < 2; ++h) {
        __syncthreads();
        if (kk == 1) {
#pragma unroll
            for (int e4 = 0; e4 < 4; ++e4) {
                const int et = h * 4 + e4;
#pragma unroll
                for (int m2 = 0; m2 < 2; ++m2)
                    *(f32x4*)&mrg[(size_t)mh * 2304 + (e4 * 16 + l15) * 36 + m2 * 16 + 4 * g] = acc[m2][et];
            }
        }
        __syncthreads();
        if (kk == 0) {
#pragma unroll
            for (int e4 = 0; e4 < 4; ++e4) {
                const int et = h * 4 + e4;
                const int e  = e0 + et * 16 + l15;
#pragma unroll
                for (int m2 = 0; m2 < 2; ++m2) {
                    const f32x4 part = *(const f32x4*)&mrg[(size_t)mh * 2304 + (e4 * 16 + l15) * 36 + m2 * 16 + 4 * g];
                    const size_t idx = ((size_t)b * Cc + e) * Nn + (mrow0 + m2 * 16 + 4 * g);
                    const float4 xin = *(const float4*)&x[idx];
                    float4 o;
                    o.x = gm * (acc[m2][et][0] + part[0]) * linv[m2][0] + xin.x;
                    o.y = gm * (acc[m2][et][1] + part[1]) * linv[m2][1] + xin.y;
                    o.z = gm * (acc[m2][et][2] + part[2]) * linv[m2][2] + xin.z;
                    o.w = gm * (acc[m2][et][3] + part[3]) * linv[m2][3] + xin.w;
                    *(float4*)&out[idx] = o;
                }
            }
        }
    }
}

extern "C" void kernel_launch(void* const* d_in, const int* in_sizes, int n_in,
                              void* d_out, int out_size, void* d_ws, size_t ws_size,
                              hipStream_t stream) {
    (void)in_sizes; (void)n_in; (void)out_size; (void)d_ws; (void)ws_size;
    const float* x  = (const float*)d_in[0];
    const float* Wq = (const float*)d_in[1];
    const float* bq = (const float*)d_in[2];
    const float* Wk = (const float*)d_in[3];
    const float* bk = (const float*)d_in[4];
    const float* Wv = (const float*)d_in[5];
    const float* bv = (const float*)d_in[6];
    const float* gm = (const float*)d_in[7];
    float* out = (float*)d_out;

    proj_kernel<<<256, 256, 0, stream>>>(x, Wq, bq, Wk, bk, Wv, bv);
    attn_kernel<<<512, 256, 0, stream>>>(x, gm, out);
}

// Round 5
// 103.168 us; speedup vs baseline: 5.6451x; 5.6451x over previous
//
#include <hip/hip_runtime.h>
#include <stdint.h>

typedef _Float16 half_t;
typedef __attribute__((ext_vector_type(8))) _Float16 f16x8;
typedef __attribute__((ext_vector_type(4))) _Float16 f16x4;
typedef __attribute__((ext_vector_type(4))) float f32x4;

#define DEVI __device__ __forceinline__

static constexpr int Bn = 4, Cc = 256, Nn = 4096, PD = 32;
static constexpr float L2E = 1.44269504089f;

// persistent f16 intermediates (module-scope device memory; fully rewritten every call)
__device__ half_t g_Q[(size_t)Bn * Nn * PD];   // [b][n][d]
__device__ half_t g_K[(size_t)Bn * Nn * PD];   // [b][n][d]  (= k^T)
__device__ half_t g_V[(size_t)Bn * Cc * Nn];   // [b][e][n]

DEVI f16x8 cvt8(float4 a, float4 b) {
    f16x8 r;
    r[0] = (_Float16)a.x; r[1] = (_Float16)a.y; r[2] = (_Float16)a.z; r[3] = (_Float16)a.w;
    r[4] = (_Float16)b.x; r[5] = (_Float16)b.y; r[6] = (_Float16)b.z; r[7] = (_Float16)b.w;
    return r;
}

// async global->LDS, 16B per lane; LDS dest is wave-uniform base + lane*16
DEVI void gll16(const void* g, void* l) {
    auto gp = (const __attribute__((address_space(1))) uint32_t*)(uintptr_t)g;
    auto lp = (__attribute__((address_space(3))) uint32_t*)(uintptr_t)l;
    __builtin_amdgcn_global_load_lds(gp, lp, 16, 0, 0);
}

// ---------------- projection: Q,K,V = W @ x (+bias), f16 outputs ----------------
__global__ __launch_bounds__(256, 1) void proj_kernel(
    const float* __restrict__ x,
    const float* __restrict__ Wq, const float* __restrict__ bq,
    const float* __restrict__ Wk, const float* __restrict__ bk,
    const float* __restrict__ Wv, const float* __restrict__ bv)
{
    __shared__ __align__(16) half_t xt[64 * 40];   // [n][c] tile, pad 32->40

    const int b    = blockIdx.x >> 6;
    const int n0   = (blockIdx.x & 63) * 64;
    const int t    = threadIdx.x;
    const int w    = t >> 6;
    const int lane = t & 63;
    const int l15  = lane & 15, g = lane >> 4;

    f32x4 qk_acc[4] = {};
    f32x4 v_acc[4][4] = {};

    const float* wrow_qk = (w < 2) ? (Wq + (size_t)(16 * w + l15) * Cc)
                                   : (Wk + (size_t)(16 * (w - 2) + l15) * Cc);

    for (int cs = 0; cs < 8; ++cs) {
        const int c0 = cs * 32;
        {
            const int nl = t & 63;
            const int cg = t >> 6;
            const float* xp = x + ((size_t)(b * Cc + c0 + cg * 8)) * Nn + n0 + nl;
            float f[8];
#pragma unroll
            for (int q = 0; q < 8; ++q) f[q] = xp[(size_t)q * Nn];
            f16x4 h0, h1;
#pragma unroll
            for (int q = 0; q < 4; ++q) { h0[q] = (_Float16)f[q]; h1[q] = (_Float16)f[q + 4]; }
            *(f16x4*)&xt[nl * 40 + cg * 8]     = h0;
            *(f16x4*)&xt[nl * 40 + cg * 8 + 4] = h1;
        }
        __syncthreads();

        f16x8 xf[4];
#pragma unroll
        for (int nf = 0; nf < 4; ++nf)
            xf[nf] = *(const f16x8*)&xt[(nf * 16 + l15) * 40 + g * 8];

        {
            const float* wp = wrow_qk + c0 + g * 8;
            const f16x8 af = cvt8(*(const float4*)wp, *(const float4*)(wp + 4));
#pragma unroll
            for (int nt = 0; nt < 4; ++nt)
                qk_acc[nt] = __builtin_amdgcn_mfma_f32_16x16x32_f16(af, xf[nt], qk_acc[nt], 0, 0, 0);
        }
#pragma unroll
        for (int et = 0; et < 4; ++et) {
            const int e = (w * 4 + et) * 16 + l15;
            const float* wp = Wv + (size_t)e * Cc + c0 + g * 8;
            const f16x8 wf = cvt8(*(const float4*)wp, *(const float4*)(wp + 4));
#pragma unroll
            for (int nf = 0; nf < 4; ++nf)
                v_acc[et][nf] = __builtin_amdgcn_mfma_f32_16x16x32_f16(xf[nf], wf, v_acc[et][nf], 0, 0, 0);
        }
        __syncthreads();
    }

    {
        const float* bias = (w < 2) ? bq : bk;
        const int dbase = 16 * (w & 1) + 4 * g;
        float bb[4];
#pragma unroll
        for (int r = 0; r < 4; ++r) bb[r] = bias[dbase + r];
        half_t* dst = (w < 2) ? g_Q : g_K;
#pragma unroll
        for (int nt = 0; nt < 4; ++nt) {
            const int n = n0 + nt * 16 + l15;
            f16x4 h;
#pragma unroll
            for (int r = 0; r < 4; ++r) h[r] = (_Float16)(qk_acc[nt][r] + bb[r]);
            *(f16x4*)&dst[((size_t)b * Nn + n) * PD + dbase] = h;
        }
    }
#pragma unroll
    for (int et = 0; et < 4; ++et) {
        const int e = (w * 4 + et) * 16 + l15;
        const float bve = bv[e];
#pragma unroll
        for (int nf = 0; nf < 4; ++nf) {
            const int n = n0 + nf * 16 + 4 * g;
            f16x4 h;
#pragma unroll
            for (int r = 0; r < 4; ++r) h[r] = (_Float16)(v_acc[et][nf][r] + bve);
            *(f16x4*)&g_V[((size_t)b * Cc + e) * Nn + n] = h;
        }
    }
}

// ---------------- fused flash attention + residual (v5 = v4 with reg-resident acc) --
// Block = 64m x 128e, 4 waves: wave (mh=w>>1, kk=w&1) handles 32m x 128e over its
// 32n half of each 64n tile.  Softmax split over n: per-iter cross-wave row-max
// exchange via LDS (folded into the ONE barrier); l and acc partials merged once
// at the end.  V staged by global_load_lds with pre-swizzled SOURCE addrs.
// NOTE: epilogue h-loop is FULLY UNROLLED — every acc[] index must be
// compile-time or the whole accumulator spills to scratch (rule #20, R4 bug).
__global__ __launch_bounds__(256, 2) void attn_kernel(
    const float* __restrict__ x, const float* __restrict__ gamma_p, float* __restrict__ out)
{
    __shared__ __align__(16) half_t V_lds[2][128 * 64];   // linear [e][n], 32KB
    __shared__ __align__(16) half_t P_lds[4][32 * 40];    // per-wave [m][n], padded
    __shared__ float hmx[2][2][32];                       // [kk][mh][m-local]
    __shared__ float lx[2][2][32];

    const int blk = blockIdx.x;
    const int grp = blk & 7;
    const int mt  = blk >> 3;
    const int b   = grp >> 1;
    const int eh  = grp & 1;
    const int e0  = eh * 128;

    const int t    = threadIdx.x;
    const int w    = t >> 6;
    const int lane = t & 63;
    const int l15  = lane & 15, g = lane >> 4;
    const int mh   = w >> 1, kk = w & 1;
    const int mrow0 = mt * 64 + mh * 32;

    const half_t* Kb  = g_K + (size_t)b * Nn * PD;
    const half_t* Vbg = g_V + (size_t)b * Cc * Nn;

    f16x8 qf[2];
#pragma unroll
    for (int m2 = 0; m2 < 2; ++m2)
        qf[m2] = *(const f16x8*)&g_Q[((size_t)b * Nn + mrow0 + m2 * 16 + l15) * PD + g * 8];

    // K pointers: wave's 32n window
    const half_t* kptr[2];
#pragma unroll
    for (int tt = 0; tt < 2; ++tt)
        kptr[tt] = Kb + (size_t)(kk * 32 + tt * 16 + l15) * PD + g * 8;

    // V gll pointers: lane covers (row = lane>>3, 16B chunk lane&7), source col
    // pre-swizzled so linear LDS == swizzled layout
    const int vrow = lane >> 3;
    const int vcol = (((lane & 7) ^ vrow) * 8);
    const half_t* vptr[4];
#pragma unroll
    for (int ch = 0; ch < 4; ++ch)
        vptr[ch] = Vbg + (size_t)(e0 + w * 32 + ch * 8 + vrow) * Nn + vcol;

    f32x4 acc[2][8] = {};                     // [m2][et]; rows m=4g+r, col e=et*16+l15
    float run_m[2] = {-1e30f, -1e30f};
    float run_l[2] = {0.f, 0.f};
    f16x8 kf[2], kfn[2];

    const int xorv = (kk * 32 + 8 * g) ^ ((l15 & 7) * 8);   // V read col offset

    // prologue: V tile 0 -> buf0, K tile 0 -> regs
#pragma unroll
    for (int ch = 0; ch < 4; ++ch)
        gll16(vptr[ch], &V_lds[0][(w * 32 + ch * 8) * 64]);
#pragma unroll
    for (int tt = 0; tt < 2; ++tt)
        kf[tt] = *(const f16x8*)kptr[tt];

    for (int i = 0; i < Nn / 64; ++i) {
        const int buf = i & 1;
        const bool more = (i < Nn / 64 - 1);

        // 1. QK^T (swapped): s[m2][tt] -> S[n = kk*32+tt*16+4g+r][m = mrow0+m2*16+l15]
        f32x4 s[2][2];
        const f32x4 zero = {0.f, 0.f, 0.f, 0.f};
#pragma unroll
        for (int m2 = 0; m2 < 2; ++m2)
#pragma unroll
            for (int tt = 0; tt < 2; ++tt)
                s[m2][tt] = __builtin_amdgcn_mfma_f32_16x16x32_f16(kf[tt], qf[m2], zero, 0, 0, 0);

        // 2. wave-local row max (8 vals, tree) + publish
        float hm[2];
#pragma unroll
        for (int m2 = 0; m2 < 2; ++m2) {
            float a0 = fmaxf(s[m2][0][0], s[m2][0][1]), a1 = fmaxf(s[m2][0][2], s[m2][0][3]);
            float a2 = fmaxf(s[m2][1][0], s[m2][1][1]), a3 = fmaxf(s[m2][1][2], s[m2][1][3]);
            float v = fmaxf(fmaxf(a0, a1), fmaxf(a2, a3));
            v = fmaxf(v, __shfl_xor(v, 16));
            v = fmaxf(v, __shfl_xor(v, 32));
            hm[m2] = v;
        }
        if (lane < 32) hmx[kk][mh][lane] = (lane < 16) ? hm[0] : hm[1];

        // 3. the ONE barrier (also drains prev gll + guards V buf reuse)
        __syncthreads();

        // 4. issue next tile (V via gll into other buf; K into regs)
        if (more) {
#pragma unroll
            for (int ch = 0; ch < 4; ++ch) {
                vptr[ch] += 64;
                gll16(vptr[ch], &V_lds[buf ^ 1][(w * 32 + ch * 8) * 64]);
            }
#pragma unroll
            for (int tt = 0; tt < 2; ++tt) {
                kptr[tt] += 64 * PD;
                kfn[tt] = *(const f16x8*)kptr[tt];
            }
        }

        // 5. combined max, defer-max, exp, l-update, P write
        float tm[2];
#pragma unroll
        for (int m2 = 0; m2 < 2; ++m2)
            tm[m2] = fmaxf(hm[m2], hmx[kk ^ 1][mh][m2 * 16 + l15]);

        const bool upd = (tm[0] > run_m[0] + 8.f) || (tm[1] > run_m[1] + 8.f);
        float alpha[2] = {1.f, 1.f};
        if (__any(upd)) {
#pragma unroll
            for (int m2 = 0; m2 < 2; ++m2) {
                const float nm = fmaxf(run_m[m2], tm[m2]);
                alpha[m2] = __builtin_amdgcn_exp2f((run_m[m2] - nm) * L2E);
                run_m[m2] = nm;
            }
            float a4[2][4];
#pragma unroll
            for (int m2 = 0; m2 < 2; ++m2)
#pragma unroll
                for (int r = 0; r < 4; ++r) a4[m2][r] = __shfl(alpha[m2], 4 * g + r);
#pragma unroll
            for (int m2 = 0; m2 < 2; ++m2)
#pragma unroll
                for (int et = 0; et < 8; ++et)
#pragma unroll
                    for (int r = 0; r < 4; ++r) acc[m2][et][r] *= a4[m2][r];
        }

#pragma unroll
        for (int m2 = 0; m2 < 2; ++m2) {
            const float nms = run_m[m2] * L2E;
            float pv[2][4];
#pragma unroll
            for (int tt = 0; tt < 2; ++tt) {
                f16x4 h;
#pragma unroll
                for (int r = 0; r < 4; ++r) {
                    pv[tt][r] = __builtin_amdgcn_exp2f(s[m2][tt][r] * L2E - nms);
                    h[r] = (_Float16)pv[tt][r];
                }
                *(f16x4*)&P_lds[w][(m2 * 16 + l15) * 40 + tt * 16 + 4 * g] = h;
            }
            float rs = ((pv[0][0] + pv[0][1]) + (pv[0][2] + pv[0][3]))
                     + ((pv[1][0] + pv[1][1]) + (pv[1][2] + pv[1][3]));
            rs += __shfl_xor(rs, 16);
            rs += __shfl_xor(rs, 32);
            run_l[m2] = run_l[m2] * alpha[m2] + rs;
        }

        // 6. PV over wave's 32n half: A = P (padded), B = V (swizzled read)
        f16x8 pf[2];
#pragma unroll
        for (int m2 = 0; m2 < 2; ++m2)
            pf[m2] = *(const f16x8*)&P_lds[w][(m2 * 16 + l15) * 40 + g * 8];

        __builtin_amdgcn_s_setprio(1);
#pragma unroll
        for (int et = 0; et < 8; ++et) {
            const int el = et * 16 + l15;
            const f16x8 vf = *(const f16x8*)&V_lds[buf][el * 64 + xorv];
            acc[0][et] = __builtin_amdgcn_mfma_f32_16x16x32_f16(pf[0], vf, acc[0][et], 0, 0, 0);
            acc[1][et] = __builtin_amdgcn_mfma_f32_16x16x32_f16(pf[1], vf, acc[1][et], 0, 0, 0);
        }
        __builtin_amdgcn_s_setprio(0);

        kf[0] = kfn[0];
        kf[1] = kfn[1];
    }

    // ---- epilogue: merge kk-pair partials, normalize, gamma, residual ----
    if (lane < 32) lx[kk][mh][lane] = (lane < 16) ? run_l[0] : run_l[1];
    __syncthreads();

    float linv[2][4];
#pragma unroll
    for (int m2 = 0; m2 < 2; ++m2) {
        const float lt  = run_l[m2] + lx[kk ^ 1][mh][m2 * 16 + l15];
        const float inv = 1.0f / lt;
#pragma unroll
        for (int r = 0; r < 4; ++r) linv[m2][r] = __shfl(inv, 4 * g + r);
    }

    const float gm = gamma_p[0];
    float* mrg = (float*)&V_lds[0][0];            // reuse V LDS (need 18KB < 32KB)
#pragma unroll                                     // FULL unroll: et stays compile-time
    for (int h = 0; h < 2; ++h) {
        __syncthreads();
        if (kk == 1) {
#pragma unroll
            for (int e4 = 0; e4 < 4; ++e4) {
                const int et = h * 4 + e4;
#pragma unroll
                for (int m2 = 0; m2 < 2; ++m2)
                    *(f32x4*)&mrg[(size_t)mh * 2304 + (e4 * 16 + l15) * 36 + m2 * 16 + 4 * g] = acc[m2][et];
            }
        }
        __syncthreads();
        if (kk == 0) {
#pragma unroll
            for (int e4 = 0; e4 < 4; ++e4) {
                const int et = h * 4 + e4;
                const int e  = e0 + et * 16 + l15;
#pragma unroll
                for (int m2 = 0; m2 < 2; ++m2) {
                    const f32x4 part = *(const f32x4*)&mrg[(size_t)mh * 2304 + (e4 * 16 + l15) * 36 + m2 * 16 + 4 * g];
                    const size_t idx = ((size_t)b * Cc + e) * Nn + (mrow0 + m2 * 16 + 4 * g);
                    const float4 xin = *(const float4*)&x[idx];
                    float4 o;
                    o.x = gm * (acc[m2][et][0] + part[0]) * linv[m2][0] + xin.x;
                    o.y = gm * (acc[m2][et][1] + part[1]) * linv[m2][1] + xin.y;
                    o.z = gm * (acc[m2][et][2] + part[2]) * linv[m2][2] + xin.z;
                    o.w = gm * (acc[m2][et][3] + part[3]) * linv[m2][3] + xin.w;
                    *(float4*)&out[idx] = o;
                }
            }
        }
    }
}

extern "C" void kernel_launch(void* const* d_in, const int* in_sizes, int n_in,
                              void* d_out, int out_size, void* d_ws, size_t ws_size,
                              hipStream_t stream) {
    (void)in_sizes; (void)n_in; (void)out_size; (void)d_ws; (void)ws_size;
    const float* x  = (const float*)d_in[0];
    const float* Wq = (const float*)d_in[1];
    const float* bq = (const float*)d_in[2];
    const float* Wk = (const float*)d_in[3];
    const float* bk = (const float*)d_in[4];
    const float* Wv = (const float*)d_in[5];
    const float* bv = (const float*)d_in[6];
    const float* gm = (const float*)d_in[7];
    float* out = (float*)d_out;

    proj_kernel<<<256, 256, 0, stream>>>(x, Wq, bq, Wk, bk, Wv, bv);
    attn_kernel<<<512, 256, 0, stream>>>(x, gm, out);
}